// Round 1
// baseline (564.497 us; speedup 1.0000x reference)
//
#include <hip/hip_runtime.h>
#include <math.h>

// Problem constants (AttentionHead_65575560675478)
constexpr int BB = 4;     // batch
constexpr int TT = 2048;  // sequence
constexpr int CC = 768;   // channels
constexpr int HH = 64;    // head dim

// ---------------------------------------------------------------------------
// Kernel 1: QKV projection. q/k/v[row, h] = sum_c x[row, c] * W[c, h]
// 16 rows of x staged in LDS per block; each wave (64 lanes) owns 4 rows and
// all three matrices, so W column loads are reused 4x and x reads are
// wave-broadcast LDS reads.
// ---------------------------------------------------------------------------
__global__ __launch_bounds__(256) void qkv_kernel(
    const float* __restrict__ x,
    const float* __restrict__ Wq,
    const float* __restrict__ Wk,
    const float* __restrict__ Wv,
    float* __restrict__ q,
    float* __restrict__ k,
    float* __restrict__ v)
{
    __shared__ float xs[16][CC];
    const int tid  = threadIdx.x;
    const int row0 = blockIdx.x * 16;

    // cooperative load of 16 x-rows (coalesced)
    for (int r = 0; r < 16; ++r) {
        for (int i = tid; i < CC; i += 256) {
            xs[r][i] = x[(size_t)(row0 + r) * CC + i];
        }
    }
    __syncthreads();

    const int h = tid & 63;       // head-dim column
    const int g = tid >> 6;       // wave id -> rows g*4 .. g*4+3
    const int r0 = g * 4;

    float accq[4] = {0.f, 0.f, 0.f, 0.f};
    float acck[4] = {0.f, 0.f, 0.f, 0.f};
    float accv[4] = {0.f, 0.f, 0.f, 0.f};

    #pragma unroll 4
    for (int c = 0; c < CC; ++c) {
        const float wq = Wq[c * HH + h];   // coalesced across the wave
        const float wk = Wk[c * HH + h];
        const float wv = Wv[c * HH + h];
        #pragma unroll
        for (int j = 0; j < 4; ++j) {
            const float xv = xs[r0 + j][c];  // wave-broadcast (no conflicts)
            accq[j] = fmaf(xv, wq, accq[j]);
            acck[j] = fmaf(xv, wk, acck[j]);
            accv[j] = fmaf(xv, wv, accv[j]);
        }
    }

    #pragma unroll
    for (int j = 0; j < 4; ++j) {
        const size_t o = (size_t)(row0 + r0 + j) * HH + h;
        q[o] = accq[j];
        k[o] = acck[j];
        v[o] = accv[j];
    }
}

// ---------------------------------------------------------------------------
// Kernel 2: causal attention for one (b, t) query row per block.
// scores[s] = 0.125 * <q_t, k_s> for s <= t, softmax in LDS, then out = P·V.
// ---------------------------------------------------------------------------
__global__ __launch_bounds__(256) void attn_kernel(
    const float* __restrict__ q,
    const float* __restrict__ k,
    const float* __restrict__ v,
    float* __restrict__ out)
{
    const int t    = blockIdx.x;
    const int b    = blockIdx.y;
    const int tid  = threadIdx.x;
    const int lane = tid & 63;
    const int wv   = tid >> 6;   // wave index 0..3

    __shared__ float4 qs4[HH / 4];
    __shared__ float  sc[TT];
    __shared__ float  red[4];
    __shared__ float  part[4][HH];

    const size_t base = (size_t)b * TT;

    if (tid < HH / 4) {
        qs4[tid] = ((const float4*)(q + (base + t) * HH))[tid];
    }
    __syncthreads();

    // ---- pass 1: scores + running max ----
    const float4* k4 = (const float4*)(k + base * HH);
    float lmax = -INFINITY;
    for (int s = tid; s <= t; s += 256) {
        const float4* kr = k4 + (size_t)s * (HH / 4);
        float acc = 0.f;
        #pragma unroll
        for (int i = 0; i < HH / 4; ++i) {
            const float4 a  = qs4[i];
            const float4 bb = kr[i];
            acc = fmaf(a.x, bb.x, acc);
            acc = fmaf(a.y, bb.y, acc);
            acc = fmaf(a.z, bb.z, acc);
            acc = fmaf(a.w, bb.w, acc);
        }
        acc *= 0.125f;   // 1/sqrt(64)
        sc[s] = acc;
        lmax = fmaxf(lmax, acc);
    }
    #pragma unroll
    for (int off = 32; off > 0; off >>= 1)
        lmax = fmaxf(lmax, __shfl_down(lmax, off, 64));
    if (lane == 0) red[wv] = lmax;
    __syncthreads();
    const float m = fmaxf(fmaxf(red[0], red[1]), fmaxf(red[2], red[3]));

    // ---- pass 2: exp + sum ----
    float lsum = 0.f;
    for (int s = tid; s <= t; s += 256) {
        const float w = __expf(sc[s] - m);
        sc[s] = w;
        lsum += w;
    }
    #pragma unroll
    for (int off = 32; off > 0; off >>= 1)
        lsum += __shfl_down(lsum, off, 64);
    __syncthreads();              // everyone has read red(max) & written sc
    if (lane == 0) red[wv] = lsum;
    __syncthreads();
    const float inv = 1.f / (red[0] + red[1] + red[2] + red[3]);

    // ---- pass 3: out[h] = sum_s sc[s] * v[s, h] ----
    const float* vb = v + base * HH;
    float acc = 0.f;
    for (int s = wv; s <= t; s += 4)
        acc = fmaf(sc[s], vb[(size_t)s * HH + lane], acc);
    part[wv][lane] = acc;
    __syncthreads();
    if (tid < HH) {
        const float r =
            (part[0][tid] + part[1][tid] + part[2][tid] + part[3][tid]) * inv;
        out[(base + t) * HH + tid] = r;
    }
}

// ---------------------------------------------------------------------------
extern "C" void kernel_launch(void* const* d_in, const int* in_sizes, int n_in,
                              void* d_out, int out_size, void* d_ws, size_t ws_size,
                              hipStream_t stream)
{
    const float* x  = (const float*)d_in[0];
    const float* Wq = (const float*)d_in[1];
    const float* Wk = (const float*)d_in[2];
    const float* Wv = (const float*)d_in[3];
    float* out = (float*)d_out;

    // workspace: q, k, v each [B*T, H] fp32 = 2 MB apiece
    float* q = (float*)d_ws;
    float* k = q + (size_t)BB * TT * HH;
    float* v = k + (size_t)BB * TT * HH;

    qkv_kernel<<<dim3((BB * TT) / 16), dim3(256), 0, stream>>>(
        x, Wq, Wk, Wv, q, k, v);

    attn_kernel<<<dim3(TT, BB), dim3(256), 0, stream>>>(q, k, v, out);
}

// Round 2
// 171.629 us; speedup vs baseline: 3.2891x; 3.2891x over previous
//
#include <hip/hip_runtime.h>
#include <math.h>

constexpr int BB = 4;     // batch
constexpr int TT = 2048;  // sequence
constexpr int CC = 768;   // channels
constexpr int HH = 64;    // head dim

typedef __attribute__((ext_vector_type(8))) short bf16x8;   // 8 bf16 = 4 VGPR
typedef __attribute__((ext_vector_type(4))) float f32x4;    // MFMA C/D

__device__ inline ushort f2bf(float f) {   // fp32 -> bf16, round-nearest-even
    uint u = __float_as_uint(f);
    u += 0x7fffu + ((u >> 16) & 1u);
    return (ushort)(u >> 16);
}

// ---------------------------------------------------------------------------
// prep_w: W[768][64] fp32  ->  Wt[mat][n][768] bf16 (transposed, k-contiguous)
// grid (12 k-chunks, 3 matrices), 256 threads
// ---------------------------------------------------------------------------
__global__ __launch_bounds__(256) void prep_w(const float* __restrict__ Wq,
                                              const float* __restrict__ Wk,
                                              const float* __restrict__ Wv,
                                              ushort* __restrict__ Wt) {
    const int k0  = blockIdx.x * 64;
    const int mat = blockIdx.y;
    const float* W = (mat == 0) ? Wq : (mat == 1) ? Wk : Wv;
    __shared__ ushort tile[64 * 66];   // [kk][n], stride 66 breaks bank stride
    const int tid = threadIdx.x;

    for (int i = tid; i < 1024; i += 256) {          // 64 rows x 16 float4
        int kk = i >> 4, c = i & 15;
        float4 f = ((const float4*)W)[(k0 + kk) * 16 + c];
        ushort* d = &tile[kk * 66 + c * 4];
        d[0] = f2bf(f.x); d[1] = f2bf(f.y); d[2] = f2bf(f.z); d[3] = f2bf(f.w);
    }
    __syncthreads();
    for (int i = tid; i < 512; i += 256) {           // 64 n-rows x 8 chunks
        int n = i >> 3, c8 = i & 7;
        bf16x8 v;
        #pragma unroll
        for (int j = 0; j < 8; ++j)
            ((ushort*)&v)[j] = tile[(c8 * 8 + j) * 66 + n];
        *(bf16x8*)&Wt[(size_t)(mat * 64 + n) * CC + k0 + c8 * 8] = v;
    }
}

// ---------------------------------------------------------------------------
// qkv_mfma: [8192 x 768] x [768 x 192] bf16 MFMA GEMM.
// Block = 32 rows, 4 waves: wave (w&1) -> 16-row half, (w>>1) -> 96-col half.
// Writes q,k row-major bf16; v transposed to vt[b][h][t] via LDS.
// ---------------------------------------------------------------------------
__global__ __launch_bounds__(256) void qkv_mfma(const float* __restrict__ x,
                                                const ushort* __restrict__ Wt,
                                                ushort* __restrict__ qg,
                                                ushort* __restrict__ kg,
                                                ushort* __restrict__ vtg) {
    __shared__ ushort xs[32 * 72];
    __shared__ ushort ws[192 * 72];
    __shared__ ushort vts[64 * 40];    // [h][t-local], stride 40 (16B aligned)
    const int tid  = threadIdx.x;
    const int row0 = blockIdx.x * 32;
    const int lane = tid & 63, w = tid >> 6;
    const int l15  = lane & 15, quad = lane >> 4;
    const int m0   = (w & 1) * 16, nbase = (w >> 1) * 96;

    f32x4 acc[6];
    #pragma unroll
    for (int i = 0; i < 6; ++i) acc[i] = (f32x4){0.f, 0.f, 0.f, 0.f};

    for (int kc = 0; kc < 12; ++kc) {
        {   // stage x chunk 32x64, fp32 -> bf16
            int row = tid >> 3, c8 = tid & 7;
            const float4* xp =
                (const float4*)(x + (size_t)(row0 + row) * CC + kc * 64 + c8 * 8);
            float4 f0 = xp[0], f1 = xp[1];
            bf16x8 v; ushort* pv = (ushort*)&v;
            pv[0]=f2bf(f0.x); pv[1]=f2bf(f0.y); pv[2]=f2bf(f0.z); pv[3]=f2bf(f0.w);
            pv[4]=f2bf(f1.x); pv[5]=f2bf(f1.y); pv[6]=f2bf(f1.z); pv[7]=f2bf(f1.w);
            *(bf16x8*)&xs[row * 72 + c8 * 8] = v;
        }
        for (int i = tid; i < 192 * 8; i += 256) {   // stage W chunk 192x64
            int n = i >> 3, c8 = i & 7;
            *(bf16x8*)&ws[n * 72 + c8 * 8] =
                *(const bf16x8*)&Wt[(size_t)n * CC + kc * 64 + c8 * 8];
        }
        __syncthreads();
        bf16x8 a0 = *(const bf16x8*)&xs[(m0 + l15) * 72 + quad * 8];
        bf16x8 a1 = *(const bf16x8*)&xs[(m0 + l15) * 72 + 32 + quad * 8];
        #pragma unroll
        for (int nt = 0; nt < 6; ++nt) {
            const ushort* wp = &ws[(nbase + nt * 16 + l15) * 72 + quad * 8];
            bf16x8 b0 = *(const bf16x8*)wp;
            bf16x8 b1 = *(const bf16x8*)(wp + 32);
            acc[nt] = __builtin_amdgcn_mfma_f32_16x16x32_bf16(a0, b0, acc[nt], 0, 0, 0);
            acc[nt] = __builtin_amdgcn_mfma_f32_16x16x32_bf16(a1, b1, acc[nt], 0, 0, 0);
        }
        __syncthreads();
    }
    // epilogue: C layout row = quad*4+r, col = l15 (+16*nt)
    #pragma unroll
    for (int nt = 0; nt < 6; ++nt) {
        int n = nbase + nt * 16 + l15;
        #pragma unroll
        for (int r = 0; r < 4; ++r) {
            int row = row0 + m0 + quad * 4 + r;
            ushort bv = f2bf(acc[nt][r]);
            if (n < 64)       qg[(size_t)row * HH + n] = bv;
            else if (n < 128) kg[(size_t)row * HH + (n - 64)] = bv;
            else              vts[(n - 128) * 40 + (m0 + quad * 4 + r)] = bv;
        }
    }
    __syncthreads();
    {   // cooperative write vt[b][h][t0..t0+31]
        int h = tid >> 2, p = tid & 3;
        int b = row0 >> 11, tl = row0 & 2047;
        bf16x8 v;
        #pragma unroll
        for (int j = 0; j < 8; ++j) ((ushort*)&v)[j] = vts[h * 40 + p * 8 + j];
        *(bf16x8*)&vtg[(size_t)b * (HH * TT) + (size_t)h * TT + tl + p * 8] = v;
    }
}

// ---------------------------------------------------------------------------
// attn_mfma: flash-style causal attention, 64-query tile per block.
// Wave w owns rows t0+16w..+15. S=QK^T and O=PV via 16x16x32 bf16 MFMA;
// online softmax in C-layout registers; P round-trips through per-wave LDS.
// ---------------------------------------------------------------------------
__global__ __launch_bounds__(256) void attn_mfma(const ushort* __restrict__ qg,
                                                 const ushort* __restrict__ kg,
                                                 const ushort* __restrict__ vtg,
                                                 float* __restrict__ out) {
    __shared__ ushort Qs[64 * 72];
    __shared__ ushort Ks[64 * 72];
    __shared__ ushort Vt[64 * 72];       // [h][s-local]
    __shared__ ushort Ps[4][16 * 72];    // per-wave P tile
    const int qt = blockIdx.x, b = blockIdx.y;
    const int t0 = qt * 64;
    const int tid  = threadIdx.x;
    const int lane = tid & 63, w = tid >> 6;
    const int l15  = lane & 15, quad = lane >> 4;

    for (int i = tid; i < 64 * 8; i += 256) {
        int row = i >> 3, c8 = i & 7;
        *(bf16x8*)&Qs[row * 72 + c8 * 8] =
            *(const bf16x8*)&qg[(size_t)(b * TT + t0 + row) * HH + c8 * 8];
    }
    __syncthreads();
    bf16x8 qa0 = *(const bf16x8*)&Qs[(w * 16 + l15) * 72 + quad * 8];
    bf16x8 qa1 = *(const bf16x8*)&Qs[(w * 16 + l15) * 72 + 32 + quad * 8];

    f32x4 po[4];
    #pragma unroll
    for (int i = 0; i < 4; ++i) po[i] = (f32x4){0.f, 0.f, 0.f, 0.f};
    float mrun[4] = {-1e30f, -1e30f, -1e30f, -1e30f};
    float lrun[4] = {0.f, 0.f, 0.f, 0.f};

    for (int st = 0; st <= qt; ++st) {
        __syncthreads();                 // all waves done with prev K/V tile
        for (int i = tid; i < 64 * 8; i += 256) {
            int row = i >> 3, c8 = i & 7;
            *(bf16x8*)&Ks[row * 72 + c8 * 8] =
                *(const bf16x8*)&kg[(size_t)(b * TT + st * 64 + row) * HH + c8 * 8];
            *(bf16x8*)&Vt[row * 72 + c8 * 8] =
                *(const bf16x8*)&vtg[(size_t)b * (HH * TT) + (size_t)row * TT + st * 64 + c8 * 8];
        }
        __syncthreads();

        // S = Q K^T  (K row-major IS the B-fragment layout for B=K^T)
        f32x4 sf[4];
        #pragma unroll
        for (int nt = 0; nt < 4; ++nt) {
            const ushort* kp = &Ks[(nt * 16 + l15) * 72 + quad * 8];
            bf16x8 b0 = *(const bf16x8*)kp;
            bf16x8 b1 = *(const bf16x8*)(kp + 32);
            f32x4 z = (f32x4){0.f, 0.f, 0.f, 0.f};
            z = __builtin_amdgcn_mfma_f32_16x16x32_bf16(qa0, b0, z, 0, 0, 0);
            sf[nt] = __builtin_amdgcn_mfma_f32_16x16x32_bf16(qa1, b1, z, 0, 0, 0);
        }

        // scale + causal mask + online softmax (row = t0+16w+4*quad+r, col = s)
        float p[4][4];
        float rm[4] = {-1e30f, -1e30f, -1e30f, -1e30f};
        #pragma unroll
        for (int nt = 0; nt < 4; ++nt) {
            int s_abs = st * 64 + nt * 16 + l15;
            #pragma unroll
            for (int r = 0; r < 4; ++r) {
                int t_abs = t0 + w * 16 + quad * 4 + r;
                float v = sf[nt][r] * 0.125f;
                v = (s_abs > t_abs) ? -1e30f : v;
                p[nt][r] = v;
                rm[r] = fmaxf(rm[r], v);
            }
        }
        float alpha[4], rs[4] = {0.f, 0.f, 0.f, 0.f};
        #pragma unroll
        for (int r = 0; r < 4; ++r) {
            float v = rm[r];
            v = fmaxf(v, __shfl_xor(v, 1, 64));
            v = fmaxf(v, __shfl_xor(v, 2, 64));
            v = fmaxf(v, __shfl_xor(v, 4, 64));
            v = fmaxf(v, __shfl_xor(v, 8, 64));
            float mnew = fmaxf(mrun[r], v);
            alpha[r] = __expf(mrun[r] - mnew);
            mrun[r] = mnew;
        }
        #pragma unroll
        for (int nt = 0; nt < 4; ++nt)
            #pragma unroll
            for (int r = 0; r < 4; ++r) {
                float e = __expf(p[nt][r] - mrun[r]);
                p[nt][r] = e;
                rs[r] += e;
            }
        #pragma unroll
        for (int r = 0; r < 4; ++r) {
            float v = rs[r];
            v += __shfl_xor(v, 1, 64);
            v += __shfl_xor(v, 2, 64);
            v += __shfl_xor(v, 4, 64);
            v += __shfl_xor(v, 8, 64);
            lrun[r] = lrun[r] * alpha[r] + v;
        }
        #pragma unroll
        for (int jj = 0; jj < 4; ++jj)
            #pragma unroll
            for (int r = 0; r < 4; ++r)
                po[jj][r] *= alpha[r];

        // P: C-layout regs -> LDS -> A-layout frags (per-wave, no barrier)
        #pragma unroll
        for (int nt = 0; nt < 4; ++nt)
            #pragma unroll
            for (int r = 0; r < 4; ++r)
                Ps[w][(quad * 4 + r) * 72 + nt * 16 + l15] = f2bf(p[nt][r]);
        bf16x8 pa0 = *(const bf16x8*)&Ps[w][l15 * 72 + quad * 8];
        bf16x8 pa1 = *(const bf16x8*)&Ps[w][l15 * 72 + 32 + quad * 8];

        // O += P V   (B-frag needs k=s contiguous -> Vt[h][s])
        #pragma unroll
        for (int jj = 0; jj < 4; ++jj) {
            const ushort* vp = &Vt[(jj * 16 + l15) * 72 + quad * 8];
            bf16x8 b0 = *(const bf16x8*)vp;
            bf16x8 b1 = *(const bf16x8*)(vp + 32);
            po[jj] = __builtin_amdgcn_mfma_f32_16x16x32_bf16(pa0, b0, po[jj], 0, 0, 0);
            po[jj] = __builtin_amdgcn_mfma_f32_16x16x32_bf16(pa1, b1, po[jj], 0, 0, 0);
        }
    }
    // epilogue: out fp32 [b][t][h]
    #pragma unroll
    for (int jj = 0; jj < 4; ++jj) {
        int h = jj * 16 + l15;
        #pragma unroll
        for (int r = 0; r < 4; ++r) {
            int t = t0 + w * 16 + quad * 4 + r;
            out[(size_t)(b * TT + t) * HH + h] = po[jj][r] / lrun[r];
        }
    }
}

// ---------------------------------------------------------------------------
extern "C" void kernel_launch(void* const* d_in, const int* in_sizes, int n_in,
                              void* d_out, int out_size, void* d_ws, size_t ws_size,
                              hipStream_t stream)
{
    const float* x  = (const float*)d_in[0];
    const float* Wq = (const float*)d_in[1];
    const float* Wk = (const float*)d_in[2];
    const float* Wv = (const float*)d_in[3];
    float* out = (float*)d_out;

    // workspace (bf16): q 1MB | k 1MB | vt 1MB | Wt 288KB
    ushort* qg  = (ushort*)d_ws;
    ushort* kg  = qg  + (size_t)BB * TT * HH;
    ushort* vtg = kg  + (size_t)BB * TT * HH;
    ushort* Wt  = vtg + (size_t)BB * TT * HH;

    prep_w  <<<dim3(12, 3),                dim3(256), 0, stream>>>(Wq, Wk, Wv, Wt);
    qkv_mfma<<<dim3((BB * TT) / 32),       dim3(256), 0, stream>>>(x, Wt, qg, kg, vtg);
    attn_mfma<<<dim3(TT / 64, BB),         dim3(256), 0, stream>>>(qg, kg, vtg, out);
}

// Round 3
// 149.055 us; speedup vs baseline: 3.7872x; 1.1514x over previous
//
#include <hip/hip_runtime.h>
#include <hip/hip_bf16.h>
#include <math.h>

constexpr int BB = 4;     // batch
constexpr int TT = 2048;  // sequence
constexpr int CC = 768;   // channels
constexpr int HH = 64;    // head dim
constexpr int NSPLIT = 4; // attention s-splits

typedef __attribute__((ext_vector_type(8))) short bf16x8;   // 8 bf16 = 4 VGPR
typedef __attribute__((ext_vector_type(4))) float f32x4;    // MFMA C/D

__device__ inline ushort f2bf(float f) {   // fp32 -> bf16 RNE (scalar)
    uint u = __float_as_uint(f);
    u += 0x7fffu + ((u >> 16) & 1u);
    return (ushort)(u >> 16);
}

__device__ inline bf16x8 cvt8(const float4 a, const float4 b) {  // packed cvt
    union { bf16x8 v; __hip_bfloat162 h[4]; } u;
    u.h[0] = __float22bfloat162_rn(make_float2(a.x, a.y));
    u.h[1] = __float22bfloat162_rn(make_float2(a.z, a.w));
    u.h[2] = __float22bfloat162_rn(make_float2(b.x, b.y));
    u.h[3] = __float22bfloat162_rn(make_float2(b.z, b.w));
    return u.v;
}

// ---------------------------------------------------------------------------
// prep_w: W[768][64] fp32 -> Wt[mat][n][768] bf16 (transposed, k-contiguous)
// ---------------------------------------------------------------------------
__global__ __launch_bounds__(256) void prep_w(const float* __restrict__ Wq,
                                              const float* __restrict__ Wk,
                                              const float* __restrict__ Wv,
                                              ushort* __restrict__ Wt) {
    const int k0  = blockIdx.x * 64;
    const int mat = blockIdx.y;
    const float* W = (mat == 0) ? Wq : (mat == 1) ? Wk : Wv;
    __shared__ ushort tile[64 * 66];
    const int tid = threadIdx.x;

    for (int i = tid; i < 1024; i += 256) {
        int kk = i >> 4, c = i & 15;
        float4 f = ((const float4*)W)[(k0 + kk) * 16 + c];
        ushort* d = &tile[kk * 66 + c * 4];
        d[0] = f2bf(f.x); d[1] = f2bf(f.y); d[2] = f2bf(f.z); d[3] = f2bf(f.w);
    }
    __syncthreads();
    for (int i = tid; i < 512; i += 256) {
        int n = i >> 3, c8 = i & 7;
        bf16x8 v;
        #pragma unroll
        for (int j = 0; j < 8; ++j)
            ((ushort*)&v)[j] = tile[(c8 * 8 + j) * 66 + n];
        *(bf16x8*)&Wt[(size_t)(mat * 64 + n) * CC + k0 + c8 * 8] = v;
    }
}

// ---------------------------------------------------------------------------
// qkv_mfma: barrier-free MFMA GEMM. Block = 32 rows; wave (w&1)->16-row half,
// (w>>1)->96-col half. A-frags direct from x (fp32->bf16 in-reg), B-frags
// direct from Wt (L2-resident). q scaled by 0.125 at write. v transposed
// through LDS to vt[b][h][t].
// ---------------------------------------------------------------------------
__global__ __launch_bounds__(256) void qkv_mfma(const float* __restrict__ x,
                                                const ushort* __restrict__ Wt,
                                                ushort* __restrict__ qg,
                                                ushort* __restrict__ kg,
                                                ushort* __restrict__ vtg) {
    __shared__ ushort vts[64 * 40];      // [h][t-local 0..31], 16B-aligned rows
    const int tid  = threadIdx.x;
    const int row0 = blockIdx.x * 32;
    const int lane = tid & 63, w = tid >> 6;
    const int l15  = lane & 15, quad = lane >> 4;
    const int m0   = (w & 1) * 16;           // row sub-tile
    const int cg   = (w >> 1) * 96;          // col group

    f32x4 acc[6];
    #pragma unroll
    for (int i = 0; i < 6; ++i) acc[i] = (f32x4){0.f, 0.f, 0.f, 0.f};

    const float* xrow = x + (size_t)(row0 + m0 + l15) * CC;
    #pragma unroll 2
    for (int kc = 0; kc < 24; ++kc) {
        const float4* xp = (const float4*)(xrow + kc * 32) + quad * 2;
        bf16x8 a = cvt8(xp[0], xp[1]);
        #pragma unroll
        for (int nt = 0; nt < 6; ++nt) {
            const ushort* wp = &Wt[(size_t)(cg + nt * 16 + l15) * CC + kc * 32 + quad * 8];
            bf16x8 bfr = *(const bf16x8*)wp;
            acc[nt] = __builtin_amdgcn_mfma_f32_16x16x32_bf16(a, bfr, acc[nt], 0, 0, 0);
        }
    }

    // epilogue: C layout row = quad*4+r, col = l15 (+16*nt)
    #pragma unroll
    for (int nt = 0; nt < 6; ++nt) {
        int n = cg + nt * 16 + l15;
        #pragma unroll
        for (int r = 0; r < 4; ++r) {
            int row = row0 + m0 + quad * 4 + r;
            float vacc = acc[nt][r];
            if (n < 64)       qg[(size_t)row * HH + n] = f2bf(vacc * 0.125f);
            else if (n < 128) kg[(size_t)row * HH + (n - 64)] = f2bf(vacc);
            else              vts[(n - 128) * 40 + (m0 + quad * 4 + r)] = f2bf(vacc);
        }
    }
    __syncthreads();
    {   // cooperative write vt[b][h][t0..t0+31]
        int h = tid >> 2, p = tid & 3;
        int b = row0 >> 11, tl = row0 & 2047;
        bf16x8 v = *(const bf16x8*)&vts[h * 40 + p * 8];
        *(bf16x8*)&vtg[(size_t)b * (HH * TT) + (size_t)h * TT + tl + p * 8] = v;
    }
}

// ---------------------------------------------------------------------------
// attn_split: flash-style causal attention, 64-query tile x s-split per block.
// Zero __syncthreads: Q/K/V fragments direct from global (L2-resident),
// per-wave LDS only for the P C-layout -> A-layout round trip.
// Writes unnormalized O + (m, l) partials per split.
// ---------------------------------------------------------------------------
__global__ __launch_bounds__(256) void attn_split(const ushort* __restrict__ qg,
                                                  const ushort* __restrict__ kg,
                                                  const ushort* __restrict__ vtg,
                                                  float* __restrict__ Op,
                                                  float* __restrict__ ml) {
    const int qt = blockIdx.x, b = blockIdx.y, split = blockIdx.z;
    const int tid  = threadIdx.x;
    const int lane = tid & 63, w = tid >> 6;
    const int l15  = lane & 15, quad = lane >> 4;
    const int t0   = qt * 64;
    const int pidx = ((b * 32 + qt) << 2) + split;

    const int ntile = qt + 1;
    const int lo = (ntile * split) >> 2;
    const int hi = (ntile * (split + 1)) >> 2;

    if (lo >= hi) {   // empty split: zero partials
        float4 z = (float4){0.f, 0.f, 0.f, 0.f};
        float4* op4 = (float4*)(Op + (size_t)pidx * 4096);
        #pragma unroll
        for (int j = 0; j < 4; ++j) op4[tid * 4 + j] = z;
        if (tid < 64) {
            ml[pidx * 128 + tid]      = -1e30f;
            ml[pidx * 128 + 64 + tid] = 0.f;
        }
        return;
    }

    __shared__ ushort Ps[4][16 * 72];

    // Q fragments direct from global (q pre-scaled by 0.125)
    const ushort* qp = &qg[(size_t)(b * TT + t0 + w * 16 + l15) * HH + quad * 8];
    bf16x8 qa0 = *(const bf16x8*)qp;
    bf16x8 qa1 = *(const bf16x8*)(qp + 32);

    f32x4 po[4];
    #pragma unroll
    for (int i = 0; i < 4; ++i) po[i] = (f32x4){0.f, 0.f, 0.f, 0.f};
    float mrun[4] = {-1e30f, -1e30f, -1e30f, -1e30f};
    float lrun[4] = {0.f, 0.f, 0.f, 0.f};

    for (int st = lo; st < hi; ++st) {
        // S = Q K^T
        f32x4 sf[4];
        #pragma unroll
        for (int nt = 0; nt < 4; ++nt) {
            const ushort* kp =
                &kg[(size_t)(b * TT + st * 64 + nt * 16 + l15) * HH + quad * 8];
            bf16x8 b0 = *(const bf16x8*)kp;
            bf16x8 b1 = *(const bf16x8*)(kp + 32);
            f32x4 z = (f32x4){0.f, 0.f, 0.f, 0.f};
            z = __builtin_amdgcn_mfma_f32_16x16x32_bf16(qa0, b0, z, 0, 0, 0);
            sf[nt] = __builtin_amdgcn_mfma_f32_16x16x32_bf16(qa1, b1, z, 0, 0, 0);
        }

        // causal mask (diagonal tile only) + online softmax
        float p[4][4];
        float rm[4] = {-1e30f, -1e30f, -1e30f, -1e30f};
        if (st == qt) {
            #pragma unroll
            for (int nt = 0; nt < 4; ++nt) {
                int s_abs = st * 64 + nt * 16 + l15;
                #pragma unroll
                for (int r = 0; r < 4; ++r) {
                    int t_abs = t0 + w * 16 + quad * 4 + r;
                    float v = (s_abs > t_abs) ? -1e30f : sf[nt][r];
                    p[nt][r] = v;
                    rm[r] = fmaxf(rm[r], v);
                }
            }
        } else {
            #pragma unroll
            for (int nt = 0; nt < 4; ++nt)
                #pragma unroll
                for (int r = 0; r < 4; ++r) {
                    p[nt][r] = sf[nt][r];
                    rm[r] = fmaxf(rm[r], sf[nt][r]);
                }
        }
        float alpha[4], rs[4] = {0.f, 0.f, 0.f, 0.f};
        #pragma unroll
        for (int r = 0; r < 4; ++r) {
            float v = rm[r];
            v = fmaxf(v, __shfl_xor(v, 1, 64));
            v = fmaxf(v, __shfl_xor(v, 2, 64));
            v = fmaxf(v, __shfl_xor(v, 4, 64));
            v = fmaxf(v, __shfl_xor(v, 8, 64));
            float mnew = fmaxf(mrun[r], v);
            alpha[r] = __expf(mrun[r] - mnew);
            mrun[r] = mnew;
        }
        #pragma unroll
        for (int nt = 0; nt < 4; ++nt)
            #pragma unroll
            for (int r = 0; r < 4; ++r) {
                float e = __expf(p[nt][r] - mrun[r]);
                p[nt][r] = e;
                rs[r] += e;
            }
        #pragma unroll
        for (int r = 0; r < 4; ++r) {
            float v = rs[r];
            v += __shfl_xor(v, 1, 64);
            v += __shfl_xor(v, 2, 64);
            v += __shfl_xor(v, 4, 64);
            v += __shfl_xor(v, 8, 64);
            lrun[r] = lrun[r] * alpha[r] + v;
        }
        #pragma unroll
        for (int jj = 0; jj < 4; ++jj)
            #pragma unroll
            for (int r = 0; r < 4; ++r)
                po[jj][r] *= alpha[r];

        // P: C-layout regs -> per-wave LDS -> A-layout frags (no barrier)
        #pragma unroll
        for (int nt = 0; nt < 4; ++nt)
            #pragma unroll
            for (int r = 0; r < 4; ++r)
                Ps[w][(quad * 4 + r) * 72 + nt * 16 + l15] = f2bf(p[nt][r]);
        bf16x8 pa0 = *(const bf16x8*)&Ps[w][l15 * 72 + quad * 8];
        bf16x8 pa1 = *(const bf16x8*)&Ps[w][l15 * 72 + 32 + quad * 8];

        // O += P V   (B-frag: vt[h][s], 8 contiguous s per lane)
        #pragma unroll
        for (int jj = 0; jj < 4; ++jj) {
            const ushort* vp =
                &vtg[(size_t)b * (HH * TT) + (size_t)(jj * 16 + l15) * TT + st * 64 + quad * 8];
            bf16x8 b0 = *(const bf16x8*)vp;
            bf16x8 b1 = *(const bf16x8*)(vp + 32);
            po[jj] = __builtin_amdgcn_mfma_f32_16x16x32_bf16(pa0, b0, po[jj], 0, 0, 0);
            po[jj] = __builtin_amdgcn_mfma_f32_16x16x32_bf16(pa1, b1, po[jj], 0, 0, 0);
        }
    }

    // write partials: unnormalized O + per-row m, l
    #pragma unroll
    for (int jj = 0; jj < 4; ++jj)
        #pragma unroll
        for (int r = 0; r < 4; ++r)
            Op[(size_t)pidx * 4096 + (w * 16 + quad * 4 + r) * 64 + jj * 16 + l15] =
                po[jj][r];
    if (l15 == 0) {
        #pragma unroll
        for (int r = 0; r < 4; ++r) {
            int row = w * 16 + quad * 4 + r;
            ml[pidx * 128 + row]      = mrun[r];
            ml[pidx * 128 + 64 + row] = lrun[r];
        }
    }
}

// ---------------------------------------------------------------------------
// attn_merge: combine NSPLIT partials per row; one wave per output row.
// ---------------------------------------------------------------------------
__global__ __launch_bounds__(256) void attn_merge(const float* __restrict__ Op,
                                                  const float* __restrict__ ml,
                                                  float* __restrict__ out) {
    const int tid = threadIdx.x;
    const int w = tid >> 6, lane = tid & 63;
    const int row = blockIdx.x * 4 + w;        // 0..8191
    const int b = row >> 11, t = row & 2047;
    const int qt = t >> 6, rl = t & 63;
    const int pbase = ((b * 32 + qt) << 2);

    float m[NSPLIT], l[NSPLIT];
    #pragma unroll
    for (int i = 0; i < NSPLIT; ++i) {
        m[i] = ml[(pbase + i) * 128 + rl];
        l[i] = ml[(pbase + i) * 128 + 64 + rl];
    }
    float M = fmaxf(fmaxf(m[0], m[1]), fmaxf(m[2], m[3]));
    float wgt[NSPLIT], L = 0.f;
    #pragma unroll
    for (int i = 0; i < NSPLIT; ++i) {
        wgt[i] = __expf(m[i] - M);
        L += wgt[i] * l[i];
    }
    float acc = 0.f;
    #pragma unroll
    for (int i = 0; i < NSPLIT; ++i)
        acc += wgt[i] * Op[(size_t)(pbase + i) * 4096 + rl * 64 + lane];
    out[(size_t)row * HH + lane] = acc / L;
}

// ---------------------------------------------------------------------------
extern "C" void kernel_launch(void* const* d_in, const int* in_sizes, int n_in,
                              void* d_out, int out_size, void* d_ws, size_t ws_size,
                              hipStream_t stream)
{
    const float* x  = (const float*)d_in[0];
    const float* Wq = (const float*)d_in[1];
    const float* Wk = (const float*)d_in[2];
    const float* Wv = (const float*)d_in[3];
    float* out = (float*)d_out;

    // ws layout (bf16/f32): qg 1MB | kg 1MB | vtg 1MB | Wt 288KB | Op 8MB | ml 256KB
    ushort* qg  = (ushort*)d_ws;
    ushort* kg  = qg  + (size_t)BB * TT * HH;
    ushort* vtg = kg  + (size_t)BB * TT * HH;
    ushort* Wt  = vtg + (size_t)BB * TT * HH;
    float*  Op  = (float*)(Wt + (size_t)3 * HH * CC);
    float*  ml  = Op + (size_t)BB * 32 * NSPLIT * 4096 / NSPLIT;  // 512*4096
    ml = Op + (size_t)512 * 4096;

    prep_w    <<<dim3(12, 3),          dim3(256), 0, stream>>>(Wq, Wk, Wv, Wt);
    qkv_mfma  <<<dim3((BB * TT) / 32), dim3(256), 0, stream>>>(x, Wt, qg, kg, vtg);
    attn_split<<<dim3(32, BB, NSPLIT), dim3(256), 0, stream>>>(qg, kg, vtg, Op, ml);
    attn_merge<<<dim3((BB * TT) / 4),  dim3(256), 0, stream>>>(Op, ml, out);
}

// Round 4
// 139.214 us; speedup vs baseline: 4.0549x; 1.0707x over previous
//
#include <hip/hip_runtime.h>
#include <hip/hip_bf16.h>
#include <math.h>

constexpr int BB = 4;     // batch
constexpr int TT = 2048;  // sequence
constexpr int CC = 768;   // channels
constexpr int HH = 64;    // head dim
constexpr int NSPLIT = 4; // attention s-splits

typedef __attribute__((ext_vector_type(8))) short bf16x8;   // 8 bf16 = 4 VGPR
typedef __attribute__((ext_vector_type(4))) float f32x4;    // MFMA C/D

__device__ inline ushort f2bf(float f) {   // fp32 -> bf16 RNE (scalar)
    uint u = __float_as_uint(f);
    u += 0x7fffu + ((u >> 16) & 1u);
    return (ushort)(u >> 16);
}

__device__ inline bf16x8 cvt8(const float4 a, const float4 b) {  // packed cvt
    union { bf16x8 v; __hip_bfloat162 h[4]; } u;
    u.h[0] = __float22bfloat162_rn(make_float2(a.x, a.y));
    u.h[1] = __float22bfloat162_rn(make_float2(a.z, a.w));
    u.h[2] = __float22bfloat162_rn(make_float2(b.x, b.y));
    u.h[3] = __float22bfloat162_rn(make_float2(b.z, b.w));
    return u.v;
}

// ---------------------------------------------------------------------------
// prep_w: W[768][64] fp32 -> Wt[mat][n][768] bf16 (transposed, k-contiguous)
// ---------------------------------------------------------------------------
__global__ __launch_bounds__(256) void prep_w(const float* __restrict__ Wq,
                                              const float* __restrict__ Wk,
                                              const float* __restrict__ Wv,
                                              ushort* __restrict__ Wt) {
    const int k0  = blockIdx.x * 64;
    const int mat = blockIdx.y;
    const float* W = (mat == 0) ? Wq : (mat == 1) ? Wk : Wv;
    __shared__ ushort tile[64 * 66];
    const int tid = threadIdx.x;

    for (int i = tid; i < 1024; i += 256) {
        int kk = i >> 4, c = i & 15;
        float4 f = ((const float4*)W)[(k0 + kk) * 16 + c];
        ushort* d = &tile[kk * 66 + c * 4];
        d[0] = f2bf(f.x); d[1] = f2bf(f.y); d[2] = f2bf(f.z); d[3] = f2bf(f.w);
    }
    __syncthreads();
    for (int i = tid; i < 512; i += 256) {
        int n = i >> 3, c8 = i & 7;
        bf16x8 v;
        #pragma unroll
        for (int j = 0; j < 8; ++j)
            ((ushort*)&v)[j] = tile[(c8 * 8 + j) * 66 + n];
        *(bf16x8*)&Wt[(size_t)(mat * 64 + n) * CC + k0 + c8 * 8] = v;
    }
}

// ---------------------------------------------------------------------------
// qkv_mfma v3: 16 rows x 192 cols per block, 4 waves col-split (48 cols each,
// 3 accs). 512 blocks = 2/CU, 8 waves/CU. A-frags direct from x (cvt in-reg,
// shared by all 4 waves via L1), B-frags direct from Wt (L2). q scaled 0.125.
// v transposed through LDS to vt[b][h][t].
// ---------------------------------------------------------------------------
__global__ __launch_bounds__(256) void qkv_mfma(const float* __restrict__ x,
                                                const ushort* __restrict__ Wt,
                                                ushort* __restrict__ qg,
                                                ushort* __restrict__ kg,
                                                ushort* __restrict__ vtg) {
    __shared__ ushort vts[64 * 24];      // [h][t-local 0..15], stride 24
    const int tid  = threadIdx.x;
    const int row0 = blockIdx.x * 16;
    const int lane = tid & 63, w = tid >> 6;
    const int l15  = lane & 15, quad = lane >> 4;
    const int cg   = w * 48;             // this wave's first output col

    f32x4 acc[3];
    #pragma unroll
    for (int i = 0; i < 3; ++i) acc[i] = (f32x4){0.f, 0.f, 0.f, 0.f};

    const float* xrow = x + (size_t)(row0 + l15) * CC;
    #pragma unroll 4
    for (int kc = 0; kc < 24; ++kc) {
        const float4* xp = (const float4*)(xrow + kc * 32) + quad * 2;
        bf16x8 a = cvt8(xp[0], xp[1]);
        #pragma unroll
        for (int nt = 0; nt < 3; ++nt) {
            bf16x8 bfr = *(const bf16x8*)
                &Wt[(size_t)(cg + nt * 16 + l15) * CC + kc * 32 + quad * 8];
            acc[nt] = __builtin_amdgcn_mfma_f32_16x16x32_bf16(a, bfr, acc[nt], 0, 0, 0);
        }
    }

    // epilogue: C layout row = quad*4+r (16-row tile), col = l15 (+16*nt)
    #pragma unroll
    for (int nt = 0; nt < 3; ++nt) {
        int n = cg + nt * 16 + l15;
        #pragma unroll
        for (int r = 0; r < 4; ++r) {
            int row = row0 + quad * 4 + r;
            float vacc = acc[nt][r];
            if (n < 64)       qg[(size_t)row * HH + n] = f2bf(vacc * 0.125f);
            else if (n < 128) kg[(size_t)row * HH + (n - 64)] = f2bf(vacc);
            else              vts[(n - 128) * 24 + (quad * 4 + r)] = f2bf(vacc);
        }
    }
    __syncthreads();
    if (tid < 128) {   // cooperative write vt[b][h][t0..t0+15]
        int h = tid >> 1, p = tid & 1;
        int b = row0 >> 11, tl = row0 & 2047;
        bf16x8 v = *(const bf16x8*)&vts[h * 24 + p * 8];
        *(bf16x8*)&vtg[(size_t)b * (HH * TT) + (size_t)h * TT + tl + p * 8] = v;
    }
}

// ---------------------------------------------------------------------------
// attn_split v3: 32-query tile (2 waves, 128 threads) x s-split per block.
// Grid (64, 4, 4) = 1024 blocks. Zero __syncthreads; fragments direct from
// global (L2-resident); per-wave LDS only for the P transpose.
// ---------------------------------------------------------------------------
__global__ __launch_bounds__(128) void attn_split(const ushort* __restrict__ qg,
                                                  const ushort* __restrict__ kg,
                                                  const ushort* __restrict__ vtg,
                                                  float* __restrict__ Op,
                                                  float* __restrict__ ml) {
    const int qt2 = blockIdx.x, b = blockIdx.y, split = blockIdx.z;
    const int tid  = threadIdx.x;
    const int lane = tid & 63, w = tid >> 6;
    const int l15  = lane & 15, quad = lane >> 4;
    const int t0   = qt2 * 32;
    const int pidx = ((b * 64 + qt2) << 2) + split;

    const int ntile = (qt2 >> 1) + 1;     // 64-wide s-tiles covering s <= t0+31
    const int lo = (ntile * split) >> 2;
    const int hi = (ntile * (split + 1)) >> 2;

    if (lo >= hi) {   // empty split: zero partials
        float4 z = (float4){0.f, 0.f, 0.f, 0.f};
        float4* op4 = (float4*)(Op + (size_t)pidx * 2048);
        #pragma unroll
        for (int j = 0; j < 4; ++j) op4[tid * 4 + j] = z;
        if (tid < 32) {
            ml[pidx * 64 + tid]      = -1e30f;
            ml[pidx * 64 + 32 + tid] = 0.f;
        }
        return;
    }

    __shared__ ushort Ps[2][16 * 72];

    // Q fragments direct from global (q pre-scaled by 0.125)
    const ushort* qp = &qg[(size_t)(b * TT + t0 + w * 16 + l15) * HH + quad * 8];
    bf16x8 qa0 = *(const bf16x8*)qp;
    bf16x8 qa1 = *(const bf16x8*)(qp + 32);

    f32x4 po[4];
    #pragma unroll
    for (int i = 0; i < 4; ++i) po[i] = (f32x4){0.f, 0.f, 0.f, 0.f};
    float mrun[4] = {-1e30f, -1e30f, -1e30f, -1e30f};
    float lrun[4] = {0.f, 0.f, 0.f, 0.f};

    for (int st = lo; st < hi; ++st) {
        // S = Q K^T
        f32x4 sf[4];
        #pragma unroll
        for (int nt = 0; nt < 4; ++nt) {
            const ushort* kp =
                &kg[(size_t)(b * TT + st * 64 + nt * 16 + l15) * HH + quad * 8];
            bf16x8 b0 = *(const bf16x8*)kp;
            bf16x8 b1 = *(const bf16x8*)(kp + 32);
            f32x4 z = (f32x4){0.f, 0.f, 0.f, 0.f};
            z = __builtin_amdgcn_mfma_f32_16x16x32_bf16(qa0, b0, z, 0, 0, 0);
            sf[nt] = __builtin_amdgcn_mfma_f32_16x16x32_bf16(qa1, b1, z, 0, 0, 0);
        }

        // causal mask (last tile of this q-tile only) + online softmax
        float p[4][4];
        float rm[4] = {-1e30f, -1e30f, -1e30f, -1e30f};
        if (st == ntile - 1) {
            #pragma unroll
            for (int nt = 0; nt < 4; ++nt) {
                int s_abs = st * 64 + nt * 16 + l15;
                #pragma unroll
                for (int r = 0; r < 4; ++r) {
                    int t_abs = t0 + w * 16 + quad * 4 + r;
                    float v = (s_abs > t_abs) ? -1e30f : sf[nt][r];
                    p[nt][r] = v;
                    rm[r] = fmaxf(rm[r], v);
                }
            }
        } else {
            #pragma unroll
            for (int nt = 0; nt < 4; ++nt)
                #pragma unroll
                for (int r = 0; r < 4; ++r) {
                    p[nt][r] = sf[nt][r];
                    rm[r] = fmaxf(rm[r], sf[nt][r]);
                }
        }
        float alpha[4], rs[4] = {0.f, 0.f, 0.f, 0.f};
        #pragma unroll
        for (int r = 0; r < 4; ++r) {
            float v = rm[r];
            v = fmaxf(v, __shfl_xor(v, 1, 64));
            v = fmaxf(v, __shfl_xor(v, 2, 64));
            v = fmaxf(v, __shfl_xor(v, 4, 64));
            v = fmaxf(v, __shfl_xor(v, 8, 64));
            float mnew = fmaxf(mrun[r], v);
            alpha[r] = __expf(mrun[r] - mnew);
            mrun[r] = mnew;
        }
        #pragma unroll
        for (int nt = 0; nt < 4; ++nt)
            #pragma unroll
            for (int r = 0; r < 4; ++r) {
                float e = __expf(p[nt][r] - mrun[r]);
                p[nt][r] = e;
                rs[r] += e;
            }
        #pragma unroll
        for (int r = 0; r < 4; ++r) {
            float v = rs[r];
            v += __shfl_xor(v, 1, 64);
            v += __shfl_xor(v, 2, 64);
            v += __shfl_xor(v, 4, 64);
            v += __shfl_xor(v, 8, 64);
            lrun[r] = lrun[r] * alpha[r] + v;
        }
        #pragma unroll
        for (int jj = 0; jj < 4; ++jj)
            #pragma unroll
            for (int r = 0; r < 4; ++r)
                po[jj][r] *= alpha[r];

        // P: C-layout regs -> per-wave LDS -> A-layout frags (no barrier)
        #pragma unroll
        for (int nt = 0; nt < 4; ++nt)
            #pragma unroll
            for (int r = 0; r < 4; ++r)
                Ps[w][(quad * 4 + r) * 72 + nt * 16 + l15] = f2bf(p[nt][r]);
        bf16x8 pa0 = *(const bf16x8*)&Ps[w][l15 * 72 + quad * 8];
        bf16x8 pa1 = *(const bf16x8*)&Ps[w][l15 * 72 + 32 + quad * 8];

        // O += P V   (B-frag: vt[h][s], 8 contiguous s per lane)
        #pragma unroll
        for (int jj = 0; jj < 4; ++jj) {
            const ushort* vp =
                &vtg[(size_t)b * (HH * TT) + (size_t)(jj * 16 + l15) * TT + st * 64 + quad * 8];
            bf16x8 b0 = *(const bf16x8*)vp;
            bf16x8 b1 = *(const bf16x8*)(vp + 32);
            po[jj] = __builtin_amdgcn_mfma_f32_16x16x32_bf16(pa0, b0, po[jj], 0, 0, 0);
            po[jj] = __builtin_amdgcn_mfma_f32_16x16x32_bf16(pa1, b1, po[jj], 0, 0, 0);
        }
    }

    // write partials: unnormalized O + per-row m, l
    #pragma unroll
    for (int jj = 0; jj < 4; ++jj)
        #pragma unroll
        for (int r = 0; r < 4; ++r)
            Op[(size_t)pidx * 2048 + (w * 16 + quad * 4 + r) * 64 + jj * 16 + l15] =
                po[jj][r];
    if (l15 == 0) {
        #pragma unroll
        for (int r = 0; r < 4; ++r) {
            int row = w * 16 + quad * 4 + r;
            ml[pidx * 64 + row]      = mrun[r];
            ml[pidx * 64 + 32 + row] = lrun[r];
        }
    }
}

// ---------------------------------------------------------------------------
// attn_merge: combine NSPLIT partials per row; one wave per output row.
// ---------------------------------------------------------------------------
__global__ __launch_bounds__(256) void attn_merge(const float* __restrict__ Op,
                                                  const float* __restrict__ ml,
                                                  float* __restrict__ out) {
    const int tid = threadIdx.x;
    const int w = tid >> 6, lane = tid & 63;
    const int row = blockIdx.x * 4 + w;        // 0..8191
    const int b = row >> 11, t = row & 2047;
    const int qt2 = t >> 5, rl = t & 31;
    const int pbase = ((b * 64 + qt2) << 2);

    float m[NSPLIT], l[NSPLIT];
    #pragma unroll
    for (int i = 0; i < NSPLIT; ++i) {
        m[i] = ml[(pbase + i) * 64 + rl];
        l[i] = ml[(pbase + i) * 64 + 32 + rl];
    }
    float M = fmaxf(fmaxf(m[0], m[1]), fmaxf(m[2], m[3]));
    float wgt[NSPLIT], L = 0.f;
    #pragma unroll
    for (int i = 0; i < NSPLIT; ++i) {
        wgt[i] = __expf(m[i] - M);
        L += wgt[i] * l[i];
    }
    float acc = 0.f;
    #pragma unroll
    for (int i = 0; i < NSPLIT; ++i)
        acc += wgt[i] * Op[(size_t)(pbase + i) * 2048 + rl * 64 + lane];
    out[(size_t)row * HH + lane] = acc / L;
}

// ---------------------------------------------------------------------------
extern "C" void kernel_launch(void* const* d_in, const int* in_sizes, int n_in,
                              void* d_out, int out_size, void* d_ws, size_t ws_size,
                              hipStream_t stream)
{
    const float* x  = (const float*)d_in[0];
    const float* Wq = (const float*)d_in[1];
    const float* Wk = (const float*)d_in[2];
    const float* Wv = (const float*)d_in[3];
    float* out = (float*)d_out;

    // ws layout: qg 1MB | kg 1MB | vtg 1MB | Wt 288KB | Op 8.4MB | ml 256KB
    ushort* qg  = (ushort*)d_ws;
    ushort* kg  = qg  + (size_t)BB * TT * HH;
    ushort* vtg = kg  + (size_t)BB * TT * HH;
    ushort* Wt  = vtg + (size_t)BB * TT * HH;
    float*  Op  = (float*)(Wt + (size_t)3 * HH * CC);
    float*  ml  = Op + (size_t)1024 * 2048;

    prep_w    <<<dim3(12, 3),           dim3(256), 0, stream>>>(Wq, Wk, Wv, Wt);
    qkv_mfma  <<<dim3((BB * TT) / 16),  dim3(256), 0, stream>>>(x, Wt, qg, kg, vtg);
    attn_split<<<dim3(64, BB, NSPLIT),  dim3(128), 0, stream>>>(qg, kg, vtg, Op, ml);
    attn_merge<<<dim3((BB * TT) / 4),   dim3(256), 0, stream>>>(Op, ml, out);
}

// Round 5
// 134.713 us; speedup vs baseline: 4.1904x; 1.0334x over previous
//
#include <hip/hip_runtime.h>
#include <hip/hip_bf16.h>
#include <math.h>

constexpr int BB = 4;     // batch
constexpr int TT = 2048;  // sequence
constexpr int CC = 768;   // channels
constexpr int HH = 64;    // head dim
constexpr int NSPLIT = 8; // attention s-splits

typedef __attribute__((ext_vector_type(8))) short bf16x8;   // 8 bf16 = 4 VGPR
typedef __attribute__((ext_vector_type(4))) float f32x4;    // MFMA C/D

__device__ inline ushort f2bf(float f) {   // fp32 -> bf16 RNE (scalar)
    uint u = __float_as_uint(f);
    u += 0x7fffu + ((u >> 16) & 1u);
    return (ushort)(u >> 16);
}

__device__ inline bf16x8 cvt8(const float4 a, const float4 b) {  // packed cvt
    union { bf16x8 v; __hip_bfloat162 h[4]; } u;
    u.h[0] = __float22bfloat162_rn(make_float2(a.x, a.y));
    u.h[1] = __float22bfloat162_rn(make_float2(a.z, a.w));
    u.h[2] = __float22bfloat162_rn(make_float2(b.x, b.y));
    u.h[3] = __float22bfloat162_rn(make_float2(b.z, b.w));
    return u.v;
}

// ---------------------------------------------------------------------------
// prep_w: W[768][64] fp32 -> Wt[mat][n][768] bf16 (transposed, k-contiguous)
// ---------------------------------------------------------------------------
__global__ __launch_bounds__(256) void prep_w(const float* __restrict__ Wq,
                                              const float* __restrict__ Wk,
                                              const float* __restrict__ Wv,
                                              ushort* __restrict__ Wt) {
    const int k0  = blockIdx.x * 64;
    const int mat = blockIdx.y;
    const float* W = (mat == 0) ? Wq : (mat == 1) ? Wk : Wv;
    __shared__ ushort tile[64 * 66];
    const int tid = threadIdx.x;

    for (int i = tid; i < 1024; i += 256) {
        int kk = i >> 4, c = i & 15;
        float4 f = ((const float4*)W)[(k0 + kk) * 16 + c];
        ushort* d = &tile[kk * 66 + c * 4];
        d[0] = f2bf(f.x); d[1] = f2bf(f.y); d[2] = f2bf(f.z); d[3] = f2bf(f.w);
    }
    __syncthreads();
    for (int i = tid; i < 512; i += 256) {
        int n = i >> 3, c8 = i & 7;
        bf16x8 v;
        #pragma unroll
        for (int j = 0; j < 8; ++j)
            ((ushort*)&v)[j] = tile[(c8 * 8 + j) * 66 + n];
        *(bf16x8*)&Wt[(size_t)(mat * 64 + n) * CC + k0 + c8 * 8] = v;
    }
}

// ---------------------------------------------------------------------------
// qkv_mfma v4: 16 rows x 192 cols per block, 4 waves col-split, with an
// explicit 4-deep register prefetch pipeline on both x and Wt so ~20 loads
// stay in flight per wave (R3 counters showed per-load latency exposure).
// ---------------------------------------------------------------------------
__global__ __launch_bounds__(256) void qkv_mfma(const float* __restrict__ x,
                                                const ushort* __restrict__ Wt,
                                                ushort* __restrict__ qg,
                                                ushort* __restrict__ kg,
                                                ushort* __restrict__ vtg) {
    __shared__ ushort vts[64 * 24];      // [h][t-local 0..15], stride 24
    const int tid  = threadIdx.x;
    const int row0 = blockIdx.x * 16;
    const int lane = tid & 63, w = tid >> 6;
    const int l15  = lane & 15, quad = lane >> 4;
    const int cg   = w * 48;             // this wave's first output col

    f32x4 acc[3];
    #pragma unroll
    for (int i = 0; i < 3; ++i) acc[i] = (f32x4){0.f, 0.f, 0.f, 0.f};

    const float*  xrow  = x + (size_t)(row0 + l15) * CC;
    const ushort* wbase = Wt + (size_t)(cg + l15) * CC + quad * 8;

    float4 xb[4][2];
    bf16x8 wb[4][3];
    #pragma unroll
    for (int i = 0; i < 4; ++i) {        // prime the pipeline: kc = 0..3
        const float4* xp = (const float4*)(xrow + i * 32) + quad * 2;
        xb[i][0] = xp[0];
        xb[i][1] = xp[1];
        #pragma unroll
        for (int nt = 0; nt < 3; ++nt)
            wb[i][nt] = *(const bf16x8*)(wbase + (size_t)nt * 16 * CC + i * 32);
    }

    #pragma unroll
    for (int kc = 0; kc < 24; ++kc) {
        const int cur = kc & 3;
        bf16x8 a  = cvt8(xb[cur][0], xb[cur][1]);
        bf16x8 w0 = wb[cur][0], w1 = wb[cur][1], w2 = wb[cur][2];
        const int nx = kc + 4;
        if (nx < 24) {                   // refill slot: loads issue before MFMAs
            const float4* xp = (const float4*)(xrow + nx * 32) + quad * 2;
            xb[cur][0] = xp[0];
            xb[cur][1] = xp[1];
            #pragma unroll
            for (int nt = 0; nt < 3; ++nt)
                wb[cur][nt] = *(const bf16x8*)(wbase + (size_t)nt * 16 * CC + nx * 32);
        }
        acc[0] = __builtin_amdgcn_mfma_f32_16x16x32_bf16(a, w0, acc[0], 0, 0, 0);
        acc[1] = __builtin_amdgcn_mfma_f32_16x16x32_bf16(a, w1, acc[1], 0, 0, 0);
        acc[2] = __builtin_amdgcn_mfma_f32_16x16x32_bf16(a, w2, acc[2], 0, 0, 0);
    }

    // epilogue: C layout row = quad*4+r (16-row tile), col = l15 (+16*nt)
    #pragma unroll
    for (int nt = 0; nt < 3; ++nt) {
        int n = cg + nt * 16 + l15;
        #pragma unroll
        for (int r = 0; r < 4; ++r) {
            int row = row0 + quad * 4 + r;
            float vacc = acc[nt][r];
            if (n < 64)       qg[(size_t)row * HH + n] = f2bf(vacc * 0.125f);
            else if (n < 128) kg[(size_t)row * HH + (n - 64)] = f2bf(vacc);
            else              vts[(n - 128) * 24 + (quad * 4 + r)] = f2bf(vacc);
        }
    }
    __syncthreads();
    if (tid < 128) {   // cooperative write vt[b][h][t0..t0+15]
        int h = tid >> 1, p = tid & 1;
        int b = row0 >> 11, tl = row0 & 2047;
        bf16x8 v = *(const bf16x8*)&vts[h * 24 + p * 8];
        *(bf16x8*)&vtg[(size_t)b * (HH * TT) + (size_t)h * TT + tl + p * 8] = v;
    }
}

// ---------------------------------------------------------------------------
// attn_split v4: 32-query tile (2 waves) x 8-way s-split. 2048 blocks.
// Per-step schedule: S-MFMAs -> prefetch K(st+1) -> issue V(st) -> softmax
// (hides K/V latency) -> P transpose -> PV-MFMAs. Zero __syncthreads.
// ---------------------------------------------------------------------------
__global__ __launch_bounds__(128) void attn_split(const ushort* __restrict__ qg,
                                                  const ushort* __restrict__ kg,
                                                  const ushort* __restrict__ vtg,
                                                  float* __restrict__ Op,
                                                  float* __restrict__ ml) {
    const int qt2 = blockIdx.x, b = blockIdx.y, split = blockIdx.z;
    const int tid  = threadIdx.x;
    const int lane = tid & 63, w = tid >> 6;
    const int l15  = lane & 15, quad = lane >> 4;
    const int t0   = qt2 * 32;
    const int pidx = ((b * 64 + qt2) << 3) + split;

    const int ntile = (qt2 >> 1) + 1;     // 64-wide s-tiles covering s <= t0+31
    const int lo = (ntile * split) >> 3;
    const int hi = (ntile * (split + 1)) >> 3;

    if (lo >= hi) {   // empty split: zero partials
        float4 z = (float4){0.f, 0.f, 0.f, 0.f};
        float4* op4 = (float4*)(Op + (size_t)pidx * 2048);
        #pragma unroll
        for (int j = 0; j < 4; ++j) op4[tid * 4 + j] = z;
        if (tid < 32) {
            ml[pidx * 64 + tid]      = -1e30f;
            ml[pidx * 64 + 32 + tid] = 0.f;
        }
        return;
    }

    __shared__ ushort Ps[2][16 * 72];

    // Q fragments direct from global (q pre-scaled by 0.125)
    const ushort* qp = &qg[(size_t)(b * TT + t0 + w * 16 + l15) * HH + quad * 8];
    bf16x8 qa0 = *(const bf16x8*)qp;
    bf16x8 qa1 = *(const bf16x8*)(qp + 32);

    const ushort* kbb = &kg[(size_t)(b * TT + l15) * HH + quad * 8];
    const ushort* vbb = &vtg[(size_t)b * (HH * TT) + (size_t)l15 * TT + quad * 8];

    f32x4 po[4];
    #pragma unroll
    for (int i = 0; i < 4; ++i) po[i] = (f32x4){0.f, 0.f, 0.f, 0.f};
    float mrun[4] = {-1e30f, -1e30f, -1e30f, -1e30f};
    float lrun[4] = {0.f, 0.f, 0.f, 0.f};

    bf16x8 kb[8], vb[8];
    #pragma unroll
    for (int nt = 0; nt < 4; ++nt) {     // prime K for st = lo
        const ushort* kp = kbb + (size_t)(lo * 64 + nt * 16) * HH;
        kb[2 * nt]     = *(const bf16x8*)kp;
        kb[2 * nt + 1] = *(const bf16x8*)(kp + 32);
    }

    for (int st = lo; st < hi; ++st) {
        // S = Q K^T (uses prefetched kb)
        f32x4 sf[4];
        #pragma unroll
        for (int nt = 0; nt < 4; ++nt) {
            f32x4 z = (f32x4){0.f, 0.f, 0.f, 0.f};
            z = __builtin_amdgcn_mfma_f32_16x16x32_bf16(qa0, kb[2 * nt], z, 0, 0, 0);
            sf[nt] = __builtin_amdgcn_mfma_f32_16x16x32_bf16(qa1, kb[2 * nt + 1], z, 0, 0, 0);
        }
        // prefetch next K (latency hidden under softmax + PV)
        if (st + 1 < hi) {
            #pragma unroll
            for (int nt = 0; nt < 4; ++nt) {
                const ushort* kp = kbb + (size_t)((st + 1) * 64 + nt * 16) * HH;
                kb[2 * nt]     = *(const bf16x8*)kp;
                kb[2 * nt + 1] = *(const bf16x8*)(kp + 32);
            }
        }
        // issue V loads for this step (consumed after softmax + P transpose)
        #pragma unroll
        for (int jj = 0; jj < 4; ++jj) {
            const ushort* vp = vbb + (size_t)(jj * 16) * TT + st * 64;
            vb[2 * jj]     = *(const bf16x8*)vp;
            vb[2 * jj + 1] = *(const bf16x8*)(vp + 32);
        }

        // causal mask (diagonal tile lives in the last split) + online softmax
        float p[4][4];
        float rm[4] = {-1e30f, -1e30f, -1e30f, -1e30f};
        if (st == ntile - 1) {
            #pragma unroll
            for (int nt = 0; nt < 4; ++nt) {
                int s_abs = st * 64 + nt * 16 + l15;
                #pragma unroll
                for (int r = 0; r < 4; ++r) {
                    int t_abs = t0 + w * 16 + quad * 4 + r;
                    float v = (s_abs > t_abs) ? -1e30f : sf[nt][r];
                    p[nt][r] = v;
                    rm[r] = fmaxf(rm[r], v);
                }
            }
        } else {
            #pragma unroll
            for (int nt = 0; nt < 4; ++nt)
                #pragma unroll
                for (int r = 0; r < 4; ++r) {
                    p[nt][r] = sf[nt][r];
                    rm[r] = fmaxf(rm[r], sf[nt][r]);
                }
        }
        float alpha[4], rs[4] = {0.f, 0.f, 0.f, 0.f};
        #pragma unroll
        for (int r = 0; r < 4; ++r) {
            float v = rm[r];
            v = fmaxf(v, __shfl_xor(v, 1, 64));
            v = fmaxf(v, __shfl_xor(v, 2, 64));
            v = fmaxf(v, __shfl_xor(v, 4, 64));
            v = fmaxf(v, __shfl_xor(v, 8, 64));
            float mnew = fmaxf(mrun[r], v);
            alpha[r] = __expf(mrun[r] - mnew);
            mrun[r] = mnew;
        }
        #pragma unroll
        for (int nt = 0; nt < 4; ++nt)
            #pragma unroll
            for (int r = 0; r < 4; ++r) {
                float e = __expf(p[nt][r] - mrun[r]);
                p[nt][r] = e;
                rs[r] += e;
            }
        #pragma unroll
        for (int r = 0; r < 4; ++r) {
            float v = rs[r];
            v += __shfl_xor(v, 1, 64);
            v += __shfl_xor(v, 2, 64);
            v += __shfl_xor(v, 4, 64);
            v += __shfl_xor(v, 8, 64);
            lrun[r] = lrun[r] * alpha[r] + v;
        }
        #pragma unroll
        for (int jj = 0; jj < 4; ++jj)
            #pragma unroll
            for (int r = 0; r < 4; ++r)
                po[jj][r] *= alpha[r];

        // P: C-layout regs -> per-wave LDS -> A-layout frags (no barrier)
        #pragma unroll
        for (int nt = 0; nt < 4; ++nt)
            #pragma unroll
            for (int r = 0; r < 4; ++r)
                Ps[w][(quad * 4 + r) * 72 + nt * 16 + l15] = f2bf(p[nt][r]);
        bf16x8 pa0 = *(const bf16x8*)&Ps[w][l15 * 72 + quad * 8];
        bf16x8 pa1 = *(const bf16x8*)&Ps[w][l15 * 72 + 32 + quad * 8];

        // O += P V (uses vb issued before softmax)
        #pragma unroll
        for (int jj = 0; jj < 4; ++jj) {
            po[jj] = __builtin_amdgcn_mfma_f32_16x16x32_bf16(pa0, vb[2 * jj], po[jj], 0, 0, 0);
            po[jj] = __builtin_amdgcn_mfma_f32_16x16x32_bf16(pa1, vb[2 * jj + 1], po[jj], 0, 0, 0);
        }
    }

    // write partials: unnormalized O + per-row m, l
    #pragma unroll
    for (int jj = 0; jj < 4; ++jj)
        #pragma unroll
        for (int r = 0; r < 4; ++r)
            Op[(size_t)pidx * 2048 + (w * 16 + quad * 4 + r) * 64 + jj * 16 + l15] =
                po[jj][r];
    if (l15 == 0) {
        #pragma unroll
        for (int r = 0; r < 4; ++r) {
            int row = w * 16 + quad * 4 + r;
            ml[pidx * 64 + row]      = mrun[r];
            ml[pidx * 64 + 32 + row] = lrun[r];
        }
    }
}

// ---------------------------------------------------------------------------
// attn_merge: combine NSPLIT partials per row; one wave per output row.
// ---------------------------------------------------------------------------
__global__ __launch_bounds__(256) void attn_merge(const float* __restrict__ Op,
                                                  const float* __restrict__ ml,
                                                  float* __restrict__ out) {
    const int tid = threadIdx.x;
    const int w = tid >> 6, lane = tid & 63;
    const int row = blockIdx.x * 4 + w;        // 0..8191
    const int b = row >> 11, t = row & 2047;
    const int qt2 = t >> 5, rl = t & 31;
    const int pbase = ((b * 64 + qt2) << 3);

    float m[NSPLIT], l[NSPLIT];
    #pragma unroll
    for (int i = 0; i < NSPLIT; ++i) {
        m[i] = ml[(pbase + i) * 64 + rl];
        l[i] = ml[(pbase + i) * 64 + 32 + rl];
    }
    float M = -1e30f;
    #pragma unroll
    for (int i = 0; i < NSPLIT; ++i) M = fmaxf(M, m[i]);
    float wgt[NSPLIT], L = 0.f;
    #pragma unroll
    for (int i = 0; i < NSPLIT; ++i) {
        wgt[i] = __expf(m[i] - M);
        L += wgt[i] * l[i];
    }
    float acc = 0.f;
    #pragma unroll
    for (int i = 0; i < NSPLIT; ++i)
        acc += wgt[i] * Op[(size_t)(pbase + i) * 2048 + rl * 64 + lane];
    out[(size_t)row * HH + lane] = acc / L;
}

// ---------------------------------------------------------------------------
extern "C" void kernel_launch(void* const* d_in, const int* in_sizes, int n_in,
                              void* d_out, int out_size, void* d_ws, size_t ws_size,
                              hipStream_t stream)
{
    const float* x  = (const float*)d_in[0];
    const float* Wq = (const float*)d_in[1];
    const float* Wk = (const float*)d_in[2];
    const float* Wv = (const float*)d_in[3];
    float* out = (float*)d_out;

    // ws layout: qg 1MB | kg 1MB | vtg 1MB | Wt 288KB | Op 16.8MB | ml 512KB
    ushort* qg  = (ushort*)d_ws;
    ushort* kg  = qg  + (size_t)BB * TT * HH;
    ushort* vtg = kg  + (size_t)BB * TT * HH;
    ushort* Wt  = vtg + (size_t)BB * TT * HH;
    float*  Op  = (float*)(Wt + (size_t)3 * HH * CC);
    float*  ml  = Op + (size_t)2048 * 2048;

    prep_w    <<<dim3(12, 3),           dim3(256), 0, stream>>>(Wq, Wk, Wv, Wt);
    qkv_mfma  <<<dim3((BB * TT) / 16),  dim3(256), 0, stream>>>(x, Wt, qg, kg, vtg);
    attn_split<<<dim3(64, BB, NSPLIT),  dim3(128), 0, stream>>>(qg, kg, vtg, Op, ml);
    attn_merge<<<dim3((BB * TT) / 4),   dim3(256), 0, stream>>>(Op, ml, out);
}